// Round 8
// baseline (228.751 us; speedup 1.0000x reference)
//
#include <hip/hip_runtime.h>
#include <float.h>

#define HEADS 8
#define DIM 64
#define BATCH 2
#define SEQ 2048
#define KNN 32
#define QT 32
#define KT 64
#define NEGF (-3.402823466e38f)

typedef float f32x4 __attribute__((ext_vector_type(4)));
typedef __bf16 bf16x8 __attribute__((ext_vector_type(8)));

union F4 { float4 v; f32x4 e; float f[4]; };
union S8 { bf16x8 b; unsigned int u[4]; unsigned short us[8]; uint4 u4; uint2 u2[2]; };

__device__ __forceinline__ unsigned short f2bf(float x) {
    unsigned int u = __float_as_uint(x);
    u = (u + 0x7fffu + ((u >> 16) & 1u)) >> 16;
    return (unsigned short)u;
}

// async global->LDS DMA, 16B per lane. gsrc is PER-LANE, ldst must be wave-uniform.
__device__ __forceinline__ void async16(const float* gsrc, float* ldst) {
    __builtin_amdgcn_global_load_lds(
        (const __attribute__((address_space(1))) unsigned int*)gsrc,
        (__attribute__((address_space(3))) unsigned int*)ldst,
        16, 0, 0);
}

// ws layout (bytes):
//   flag  @ 0
//   knB   @ 1024            bf16 (B,S,D)        512 KB
//   vT    @ 1024 + 512K     bf16 (B,D,S)        512 KB
//   qnB   @ 1024 + 1M       bf16 (B,H,S,D)      4 MB
//   maccG @ 1024 + 5M       f32  (B,H,S,D)      8 MB
//   mG    @ 1024 + 13M      f32  (B,H,S)        128 KB
//   lG    @ 1024 + 13M+256K f32  (B,H,S)        128 KB

__global__ __launch_bounds__(256) void prep_kernel(const float* __restrict__ k,
                                                   const float* __restrict__ v,
                                                   const unsigned char* __restrict__ mmraw,
                                                   unsigned short* __restrict__ knB,
                                                   unsigned short* __restrict__ vT,
                                                   int* __restrict__ flag) {
    __shared__ float vt_s[64][65];
    const int w = threadIdx.x >> 6, lane = threadIdx.x & 63;
    const int s0 = blockIdx.x * 64;       // global row index b*SEQ+s
    const int b = s0 >> 11;
    for (int rr = 0; rr < 16; rr++) {
        const int sl = w * 16 + rr;
        const int row = s0 + sl;
        float kv = k[(size_t)row * DIM + lane];
        float ssq = kv * kv;
        #pragma unroll
        for (int m = 1; m < 64; m <<= 1) ssq += __shfl_xor(ssq, m);
        float kn = kv / fmaxf(sqrtf(ssq), 1e-12f);
        knB[(size_t)row * DIM + lane] = f2bf(kn);
        vt_s[sl][lane] = v[(size_t)row * DIM + lane];
    }
    __syncthreads();
    {   // transposed V write: thread -> (d, 16-s chunk), 32B contiguous stores
        const int d = threadIdx.x >> 2;
        const int sc = (threadIdx.x & 3) * 16;
        const int s_base = s0 & 2047;
        unsigned short tmp[16];
        #pragma unroll
        for (int e = 0; e < 16; e++) tmp[e] = f2bf(vt_s[sc + e][d]);
        unsigned short* dst = vT + ((size_t)b * DIM + d) * SEQ + s_base + sc;
        *(uint4*)dst = *(uint4*)&tmp[0];
        *(uint4*)(dst + 8) = *(uint4*)&tmp[8];
    }
    if (blockIdx.x == 0 && w == 0) {
        int bad = 0;
        #pragma unroll
        for (int t = 0; t < 8; t++) {
            int idx = t * 64 + lane;
            if ((idx & 3) != 0 && mmraw[idx] != 0) bad = 1;
        }
        unsigned long long anybad = __ballot(bad);
        if (lane == 0) flag[0] = (anybad == 0ULL) ? 1 : 0;
    }
}

// Mem-branch streamer: 1 row per wave, LDS-staged via global_load_lds (VGPR-free
// batched DMA: 16 issues, ONE vmcnt wait), predicated on mem_mask bits.
__global__ __launch_bounds__(128) void mem_kernel(
    const float* __restrict__ q,           // B,H,S,D
    const float* __restrict__ scale_param, // H
    const float* __restrict__ mem_kv,      // B,H,S,KNN,2,D
    const void*  __restrict__ mem_mask,    // B,H,S,KNN
    const int*   __restrict__ flagp,
    unsigned short* __restrict__ qnB,      // out: bf16 normalized q
    float* __restrict__ maccG,             // out: (B,H,S,D) weighted mem_v (unnormalized)
    float* __restrict__ mG,                // out: (B,H,S) row max
    float* __restrict__ lG)                // out: (B,H,S) row sum
{
    __shared__ float ldsbuf[2][4096];      // 16 KB per wave
    const int w = threadIdx.x >> 6, lane = threadIdx.x & 63;
    const int i16 = lane & 15;        // d-quarter
    const int kv  = (lane >> 4) & 1;  // 0 = k-part, 1 = v-part
    const int h2  = lane >> 5;        // j parity
    const int mask_is_int = flagp[0];
    const int gid = blockIdx.x * 2 + w;    // one row per wave
    const float scale = __expf(scale_param[(gid >> 11) & 7]);
    float* ldsrow = &ldsbuf[w][0];

    // issue q load early (independent)
    float qv = q[(size_t)gid * DIM + lane];

    // mask ballot (bits 0..31 = j)
    size_t mmrow = (size_t)gid * KNN;
    bool mybit = mask_is_int ? (((const int*)mem_mask)[mmrow + (lane & 31)] != 0)
                             : (((const unsigned char*)mem_mask)[mmrow + (lane & 31)] != 0);
    const unsigned int mb = (unsigned int)__ballot(mybit);

    // batched async DMA: 16 chunk issues, predicated per mask bit
    const float* rowp = mem_kv + (size_t)gid * (KNN * 2 * DIM);
    #pragma unroll
    for (int t = 0; t < 16; t++) {
        const int j = 2 * t + h2;
        if ((mb >> j) & 1u)
            async16(rowp + (size_t)(t * 64 + lane) * 4, ldsrow + t * 256);
    }

    // q l2-norm while DMA is in flight
    float ssq = qv * qv;
    #pragma unroll
    for (int m2 = 1; m2 < 64; m2 <<= 1) ssq += __shfl_xor(ssq, m2);
    float qn = qv / fmaxf(sqrtf(ssq), 1e-12f);
    qnB[(size_t)gid * DIM + lane] = f2bf(qn);
    F4 qd;
    #pragma unroll
    for (int e = 0; e < 4; e++) qd.f[e] = __shfl(qn, i16 * 4 + e);

    asm volatile("s_waitcnt vmcnt(0)" ::: "memory");
    __builtin_amdgcn_sched_barrier(0);

    // pass 1: dots (k-lanes meaningful), gated reads (stale LDS in masked slots)
    float pj[16];
    #pragma unroll
    for (int t = 0; t < 16; t++) {
        F4 dv; dv.v = *(const float4*)(ldsrow + t * 256 + lane * 4);
        const int j = 2 * t + h2;
        const bool bit = (mb >> j) & 1u;
        #pragma unroll
        for (int e = 0; e < 4; e++) dv.f[e] = bit ? dv.f[e] : 0.f;
        float part = dv.f[0] * qd.f[0] + dv.f[1] * qd.f[1]
                   + dv.f[2] * qd.f[2] + dv.f[3] * qd.f[3];
        part += __shfl_xor(part, 1);
        part += __shfl_xor(part, 2);
        part += __shfl_xor(part, 4);
        part += __shfl_xor(part, 8);
        pj[t] = bit ? part * scale : NEGF;
    }
    // row max over 32 j (combine parities via xor 32); valid in k-lanes
    float mx = pj[0];
    #pragma unroll
    for (int t = 1; t < 16; t++) mx = fmaxf(mx, pj[t]);
    mx = fmaxf(mx, __shfl_xor(mx, 32));
    float ls = 0.f;
    #pragma unroll
    for (int t = 0; t < 16; t++) {
        float p = __expf(pj[t] - mx);
        pj[t] = p;
        ls += p;
    }
    ls += __shfl_xor(ls, 32);

    // pass 2: weighted V (v-lanes), p pulled from partner k-lane via xor 16
    float a0 = 0.f, a1 = 0.f, a2 = 0.f, a3 = 0.f;
    #pragma unroll
    for (int t = 0; t < 16; t++) {
        F4 dv; dv.v = *(const float4*)(ldsrow + t * 256 + lane * 4);
        const int j = 2 * t + h2;
        const bool bit = (mb >> j) & 1u;
        #pragma unroll
        for (int e = 0; e < 4; e++) dv.f[e] = bit ? dv.f[e] : 0.f;
        float p = __shfl_xor(pj[t], 16);
        a0 += p * dv.f[0];
        a1 += p * dv.f[1];
        a2 += p * dv.f[2];
        a3 += p * dv.f[3];
    }
    a0 += __shfl_xor(a0, 32);
    a1 += __shfl_xor(a1, 32);
    a2 += __shfl_xor(a2, 32);
    a3 += __shfl_xor(a3, 32);
    if (kv == 1 && h2 == 0) {
        F4 o; o.f[0] = a0; o.f[1] = a1; o.f[2] = a2; o.f[3] = a3;
        *(float4*)(maccG + (size_t)gid * DIM + i16 * 4) = o.v;
    }
    if (lane == 0) { mG[gid] = mx; lG[gid] = ls; }
}

__global__ __launch_bounds__(256) void flash_kernel(
    const float* __restrict__ scale_param,  // H
    const float* __restrict__ mask,         // B,S float
    const unsigned short* __restrict__ knB, // B,S,D bf16 (l2-normed k)
    const unsigned short* __restrict__ vT,  // B,D,S bf16
    const unsigned short* __restrict__ qnB, // B,H,S,D bf16 (l2-normed q)
    const float* __restrict__ maccG,        // B,H,S,D mem-branch acc
    const float* __restrict__ mG,           // B,H,S
    const float* __restrict__ lG,           // B,H,S
    float* __restrict__ out)                // B,H,S,D
{
    __shared__ float maccs[QT][DIM + 4];
    __shared__ float mmem_s[QT], lmem_s[QT];
    __shared__ unsigned short fragbuf[4][2][2][4][16][8]; // per-wave P in B-frag layout
    __shared__ float corr_s[4][QT];
    __shared__ float mlw[4][2][QT];
    __shared__ float linv_s[QT];

    const int tid = threadIdx.x;
    const int w = tid >> 6;
    const int lane = tid & 63;
    const int g = lane >> 4;
    const int c = lane & 15;
    const int bid = blockIdx.x;
    const int qt = 63 - (bid & 63);       // heavy tiles first
    const int bh = bid >> 6;
    const int b = bh >> 3;
    const int h = bh & 7;
    const int i0 = qt * QT;

    const float scale = __expf(scale_param[h]);

    // ---- load mem-branch partials into LDS; q A-frags from qnB ----
    {
        int i = tid >> 3, d0 = (tid & 7) * 8;
        const float* src = maccG + ((size_t)bh * SEQ + i0 + i) * DIM + d0;
        *(float4*)&maccs[i][d0]     = *(const float4*)src;
        *(float4*)&maccs[i][d0 + 4] = *(const float4*)(src + 4);
        if (tid < QT) {
            mmem_s[tid] = mG[(size_t)bh * SEQ + i0 + tid];
            lmem_s[tid] = lG[(size_t)bh * SEQ + i0 + tid];
        }
    }
    bf16x8 qa[2][2];
    #pragma unroll
    for (int mt = 0; mt < 2; mt++)
        #pragma unroll
        for (int kc = 0; kc < 2; kc++) {
            S8 t;
            t.u4 = *(const uint4*)(qnB + ((size_t)bh * SEQ + i0 + mt * 16 + c) * DIM + kc * 32 + g * 8);
            qa[mt][kc] = t.b;
        }

    // ---------------- Flash over key tiles (waves split jt) ----------------
    f32x4 oacc[4][2];
    #pragma unroll
    for (int mtd = 0; mtd < 4; mtd++)
        #pragma unroll
        for (int ni = 0; ni < 2; ni++)
            #pragma unroll
            for (int r = 0; r < 4; r++) oacc[mtd][ni][r] = 0.f;
    float mrow[2][4], lrow[2][4];
    #pragma unroll
    for (int mt = 0; mt < 2; mt++)
        #pragma unroll
        for (int r = 0; r < 4; r++) { mrow[mt][r] = NEGF; lrow[mt][r] = 0.f; }

    const int nkt = ((i0 + QT - 1) >> 6) + 1;
    const unsigned short* knBb = knB + (size_t)b * SEQ * DIM;
    const unsigned short* vTb  = vT  + (size_t)b * DIM * SEQ;

    for (int jt = w; jt < nkt; jt += 4) {
        const int jb = jt * KT;

        bf16x8 va[4][2];
        #pragma unroll
        for (int mtd = 0; mtd < 4; mtd++)
            #pragma unroll
            for (int kk2 = 0; kk2 < 2; kk2++) {
                const unsigned short* vp = vTb + (size_t)(mtd * 16 + c) * SEQ + jb + kk2 * 32 + 4 * g;
                S8 t; t.u2[0] = *(const uint2*)vp; t.u2[1] = *(const uint2*)(vp + 16);
                va[mtd][kk2] = t.b;
            }

        f32x4 sacc[2][4];
        #pragma unroll
        for (int mt = 0; mt < 2; mt++)
            #pragma unroll
            for (int nt = 0; nt < 4; nt++)
                #pragma unroll
                for (int r = 0; r < 4; r++) sacc[mt][nt][r] = 0.f;
        #pragma unroll
        for (int kc = 0; kc < 2; kc++) {
            #pragma unroll
            for (int nt = 0; nt < 4; nt++) {
                S8 kb; kb.u4 = *(const uint4*)(knBb + (size_t)(jb + nt * 16 + c) * DIM + kc * 32 + g * 8);
                #pragma unroll
                for (int mt = 0; mt < 2; mt++)
                    sacc[mt][nt] = __builtin_amdgcn_mfma_f32_16x16x32_bf16(qa[mt][kc], kb.b, sacc[mt][nt], 0, 0, 0);
            }
        }

        float mv4[4];
        #pragma unroll
        for (int nt = 0; nt < 4; nt++) mv4[nt] = mask[b * SEQ + jb + nt * 16 + c];
        const bool docausal = (jb + 63 > i0);
        float corr[2][4];
        #pragma unroll
        for (int mt = 0; mt < 2; mt++) {
            #pragma unroll
            for (int nt = 0; nt < 4; nt++)
                #pragma unroll
                for (int r = 0; r < 4; r++) {
                    float s = sacc[mt][nt][r] * scale + NEGF * (1.f - mv4[nt]);
                    if (docausal) {
                        int j = jb + nt * 16 + c;
                        int i = i0 + mt * 16 + 4 * g + r;
                        if (j > i) s = NEGF;
                    }
                    sacc[mt][nt][r] = s;
                }
            #pragma unroll
            for (int r = 0; r < 4; r++) {
                float rmax = fmaxf(fmaxf(sacc[mt][0][r], sacc[mt][1][r]),
                                   fmaxf(sacc[mt][2][r], sacc[mt][3][r]));
                #pragma unroll
                for (int m2 = 1; m2 < 16; m2 <<= 1) rmax = fmaxf(rmax, __shfl_xor(rmax, m2));
                float mnew = fmaxf(mrow[mt][r], rmax);
                corr[mt][r] = __expf(mrow[mt][r] - mnew);
                mrow[mt][r] = mnew;
            }
        }

        #pragma unroll
        for (int mt = 0; mt < 2; mt++) {
            float psum[4] = {0.f, 0.f, 0.f, 0.f};
            #pragma unroll
            for (int nt = 0; nt < 4; nt++)
                #pragma unroll
                for (int r = 0; r < 4; r++) {
                    float p = __expf(sacc[mt][nt][r] - mrow[mt][r]);
                    psum[r] += p;
                    fragbuf[w][mt][nt >> 1][c >> 2][4 * g + r][(c & 3) + 4 * (nt & 1)] = f2bf(p);
                }
            #pragma unroll
            for (int r = 0; r < 4; r++) {
                float ps = psum[r];
                #pragma unroll
                for (int m2 = 1; m2 < 16; m2 <<= 1) ps += __shfl_xor(ps, m2);
                lrow[mt][r] = lrow[mt][r] * corr[mt][r] + ps;
            }
        }

        if (c == 0) {
            #pragma unroll
            for (int mt = 0; mt < 2; mt++)
                #pragma unroll
                for (int r = 0; r < 4; r++)
                    corr_s[w][mt * 16 + 4 * g + r] = corr[mt][r];
        }
        float cf0 = corr_s[w][c];
        float cf1 = corr_s[w][16 + c];
        #pragma unroll
        for (int mtd = 0; mtd < 4; mtd++)
            #pragma unroll
            for (int r = 0; r < 4; r++) { oacc[mtd][0][r] *= cf0; oacc[mtd][1][r] *= cf1; }

        #pragma unroll
        for (int kk2 = 0; kk2 < 2; kk2++)
            #pragma unroll
            for (int ni = 0; ni < 2; ni++) {
                S8 pb; pb.u4 = *(const uint4*)&fragbuf[w][ni][kk2][g][c][0];
                #pragma unroll
                for (int mtd = 0; mtd < 4; mtd++)
                    oacc[mtd][ni] = __builtin_amdgcn_mfma_f32_16x16x32_bf16(va[mtd][kk2], pb.b, oacc[mtd][ni], 0, 0, 0);
            }
    }

    // ---------------- merge: 4 wave-partials + mem branch ----------------
    if (c == 0) {
        #pragma unroll
        for (int mt = 0; mt < 2; mt++)
            #pragma unroll
            for (int r = 0; r < 4; r++) {
                mlw[w][0][mt * 16 + 4 * g + r] = mrow[mt][r];
                mlw[w][1][mt * 16 + 4 * g + r] = lrow[mt][r];
            }
    }
    __syncthreads();
    {
        int i = tid >> 3;
        int d0 = (tid & 7) * 8;
        float mM = mmem_s[i];
        #pragma unroll
        for (int w2 = 0; w2 < 4; w2++) mM = fmaxf(mM, mlw[w2][0][i]);
        float em = __expf(mmem_s[i] - mM);
        float L = lmem_s[i] * em;
        #pragma unroll
        for (int w2 = 0; w2 < 4; w2++) L += mlw[w2][1][i] * __expf(mlw[w2][0][i] - mM);
        #pragma unroll
        for (int e = 0; e < 8; e++) maccs[i][d0 + e] *= em;
        if ((tid & 7) == 0) linv_s[i] = 1.f / L;
        if ((tid & 7) == 1) corr_s[0][i] = mM;   // stash global max
    }
    __syncthreads();
    float ew0 = __expf(mlw[w][0][c]      - corr_s[0][c]);
    float ew1 = __expf(mlw[w][0][16 + c] - corr_s[0][16 + c]);
    for (int w2 = 0; w2 < 4; w2++) {
        if (w == w2) {
            #pragma unroll
            for (int mtd = 0; mtd < 4; mtd++)
                #pragma unroll
                for (int r = 0; r < 4; r++) {
                    maccs[c][mtd * 16 + 4 * g + r]      += oacc[mtd][0][r] * ew0;
                    maccs[16 + c][mtd * 16 + 4 * g + r] += oacc[mtd][1][r] * ew1;
                }
        }
        __syncthreads();
    }
    {
        int i = tid >> 3;
        int d0 = (tid & 7) * 8;
        float inv = linv_s[i];
        F4 o0, o1;
        o0.v = *(const float4*)&maccs[i][d0];
        o1.v = *(const float4*)&maccs[i][d0 + 4];
        #pragma unroll
        for (int e = 0; e < 4; e++) { o0.f[e] *= inv; o1.f[e] *= inv; }
        float* op = out + ((size_t)bh * SEQ + i0 + i) * DIM + d0;
        *(float4*)op = o0.v;
        *(float4*)(op + 4) = o1.v;
    }
}

extern "C" void kernel_launch(void* const* d_in, const int* in_sizes, int n_in,
                              void* d_out, int out_size, void* d_ws, size_t ws_size,
                              hipStream_t stream) {
    const float* q           = (const float*)d_in[0];
    const float* k           = (const float*)d_in[1];
    const float* v           = (const float*)d_in[2];
    const float* scale_param = (const float*)d_in[3];
    const float* mem_kv      = (const float*)d_in[4];
    const float* mask        = (const float*)d_in[5];
    const void*  mem_mask    = d_in[6];
    float* out = (float*)d_out;

    char* base = (char*)d_ws;
    int* flag           = (int*)base;
    unsigned short* knB = (unsigned short*)(base + 1024);
    unsigned short* vT  = (unsigned short*)(base + 1024 + (512ull << 10));
    unsigned short* qnB = (unsigned short*)(base + 1024 + (1ull << 20));
    float* maccG        = (float*)(base + 1024 + (5ull << 20));
    float* mG           = (float*)(base + 1024 + (13ull << 20));
    float* lG           = (float*)(base + 1024 + (13ull << 20) + (256ull << 10));

    prep_kernel<<<dim3(BATCH * SEQ / 64), dim3(256), 0, stream>>>(
        k, v, (const unsigned char*)mem_mask, knB, vT, flag);
    mem_kernel<<<dim3(BATCH * HEADS * SEQ / 2), dim3(128), 0, stream>>>(
        q, scale_param, mem_kv, mem_mask, flag, qnB, maccG, mG, lG);
    flash_kernel<<<dim3(BATCH * HEADS * (SEQ / QT)), dim3(256), 0, stream>>>(
        scale_param, mask, knB, vT, qnB, maccG, mG, lG, out);
}

// Round 9
// 160.292 us; speedup vs baseline: 1.4271x; 1.4271x over previous
//
#include <hip/hip_runtime.h>
#include <float.h>

#define HEADS 8
#define DIM 64
#define BATCH 2
#define SEQ 2048
#define KNN 32
#define QT 32
#define KT 64
#define NEGF (-3.402823466e38f)

typedef float f32x4 __attribute__((ext_vector_type(4)));
typedef __bf16 bf16x8 __attribute__((ext_vector_type(8)));

union F4 { float4 v; f32x4 e; float f[4]; };
union S8 { bf16x8 b; unsigned int u[4]; unsigned short us[8]; uint4 u4; uint2 u2[2]; };

__device__ __forceinline__ unsigned short f2bf(float x) {
    unsigned int u = __float_as_uint(x);
    u = (u + 0x7fffu + ((u >> 16) & 1u)) >> 16;
    return (unsigned short)u;
}

// ws layout (bytes):
//   flag  @ 0
//   knB   @ 1024            bf16 (B,S,D)        512 KB
//   vT    @ 1024 + 512K     bf16 (B,D,S)        512 KB
//   qnB   @ 1024 + 1M       bf16 (B,H,S,D)      4 MB
//   maccG @ 1024 + 5M       f32  (B,H,S,D)      8 MB
//   mG    @ 1024 + 13M      f32  (B,H,S)        128 KB
//   lG    @ 1024 + 13M+256K f32  (B,H,S)        128 KB

__global__ __launch_bounds__(256) void prep_kernel(const float* __restrict__ k,
                                                   const float* __restrict__ v,
                                                   const unsigned char* __restrict__ mmraw,
                                                   unsigned short* __restrict__ knB,
                                                   unsigned short* __restrict__ vT,
                                                   int* __restrict__ flag) {
    __shared__ float vt_s[64][65];
    const int w = threadIdx.x >> 6, lane = threadIdx.x & 63;
    const int s0 = blockIdx.x * 64;       // global row index b*SEQ+s
    const int b = s0 >> 11;
    for (int rr = 0; rr < 16; rr++) {
        const int sl = w * 16 + rr;
        const int row = s0 + sl;
        float kv = k[(size_t)row * DIM + lane];
        float ssq = kv * kv;
        #pragma unroll
        for (int m = 1; m < 64; m <<= 1) ssq += __shfl_xor(ssq, m);
        float kn = kv / fmaxf(sqrtf(ssq), 1e-12f);
        knB[(size_t)row * DIM + lane] = f2bf(kn);
        vt_s[sl][lane] = v[(size_t)row * DIM + lane];
    }
    __syncthreads();
    {   // transposed V write: thread -> (d, 16-s chunk), 32B contiguous stores
        const int d = threadIdx.x >> 2;
        const int sc = (threadIdx.x & 3) * 16;
        const int s_base = s0 & 2047;
        unsigned short tmp[16];
        #pragma unroll
        for (int e = 0; e < 16; e++) tmp[e] = f2bf(vt_s[sc + e][d]);
        unsigned short* dst = vT + ((size_t)b * DIM + d) * SEQ + s_base + sc;
        *(uint4*)dst = *(uint4*)&tmp[0];
        *(uint4*)(dst + 8) = *(uint4*)&tmp[8];
    }
    if (blockIdx.x == 0 && w == 0) {
        int bad = 0;
        #pragma unroll
        for (int t = 0; t < 8; t++) {
            int idx = t * 64 + lane;
            if ((idx & 3) != 0 && mmraw[idx] != 0) bad = 1;
        }
        unsigned long long anybad = __ballot(bad);
        if (lane == 0) flag[0] = (anybad == 0ULL) ? 1 : 0;
    }
}

// Mem-branch streamer v3: 1 row/wave, online softmax over 4 groups of 4 chunks,
// double-buffered (dat[2][4]), unconditional redirect loads (constant vmcnt),
// no LDS, VGPR-lean for high occupancy.
#define LOADG(B, G)                                                              \
    _Pragma("unroll")                                                            \
    for (int tt = 0; tt < 4; tt++) {                                             \
        const int t_ = 4 * (G) + tt;                                             \
        const int j_ = 2 * t_ + h2;                                              \
        const float* src_ = ((mb >> j_) & 1u) ? (lanep + t_ * 256) : lanep;      \
        dat[B][tt].e = *(const f32x4*)src_;                                      \
    }

#define COMPUTE(B, G) {                                                          \
    float sv[4];                                                                 \
    _Pragma("unroll")                                                            \
    for (int tt = 0; tt < 4; tt++) {                                             \
        const int t_ = 4 * (G) + tt;                                             \
        const int j_ = 2 * t_ + h2;                                              \
        const bool bit_ = (mb >> j_) & 1u;                                       \
        _Pragma("unroll")                                                        \
        for (int e = 0; e < 4; e++) dat[B][tt].f[e] = bit_ ? dat[B][tt].f[e] : 0.f; \
        float part = dat[B][tt].f[0] * qd.f[0] + dat[B][tt].f[1] * qd.f[1]       \
                   + dat[B][tt].f[2] * qd.f[2] + dat[B][tt].f[3] * qd.f[3];      \
        part += __shfl_xor(part, 1);                                             \
        part += __shfl_xor(part, 2);                                             \
        part += __shfl_xor(part, 4);                                             \
        part += __shfl_xor(part, 8);                                             \
        sv[tt] = bit_ ? part * scale : NEGF;                                     \
    }                                                                            \
    float gm = fmaxf(fmaxf(sv[0], sv[1]), fmaxf(sv[2], sv[3]));                  \
    gm = fmaxf(gm, __shfl_xor(gm, 32));                                          \
    float mnew = fmaxf(mrun, gm);                                                \
    float corr = __expf(mrun - mnew);                                            \
    float cv = __shfl_xor(corr, 16);                                             \
    a0 *= cv; a1 *= cv; a2 *= cv; a3 *= cv;                                      \
    float lg = 0.f;                                                              \
    _Pragma("unroll")                                                            \
    for (int tt = 0; tt < 4; tt++) {                                             \
        float p = __expf(sv[tt] - mnew);                                         \
        lg += p;                                                                 \
        float pv = __shfl_xor(p, 16);                                            \
        a0 += pv * dat[B][tt].f[0];                                              \
        a1 += pv * dat[B][tt].f[1];                                              \
        a2 += pv * dat[B][tt].f[2];                                              \
        a3 += pv * dat[B][tt].f[3];                                              \
    }                                                                            \
    lrun = lrun * corr + lg;                                                     \
    mrun = mnew; }

__global__ __launch_bounds__(256, 6) void mem_kernel(
    const float* __restrict__ q,           // B,H,S,D
    const float* __restrict__ scale_param, // H
    const float* __restrict__ mem_kv,      // B,H,S,KNN,2,D
    const void*  __restrict__ mem_mask,    // B,H,S,KNN
    const int*   __restrict__ flagp,
    unsigned short* __restrict__ qnB,      // out: bf16 normalized q
    float* __restrict__ maccG,             // out: (B,H,S,D) weighted mem_v (unnormalized)
    float* __restrict__ mG,                // out: (B,H,S) row max
    float* __restrict__ lG)                // out: (B,H,S) row sum
{
    const int w = threadIdx.x >> 6, lane = threadIdx.x & 63;
    const int i16 = lane & 15;        // d-quarter
    const int kv  = (lane >> 4) & 1;  // 0 = k-part, 1 = v-part
    const int h2  = lane >> 5;        // j parity
    const int mask_is_int = flagp[0];
    const int gid = blockIdx.x * 4 + w;    // one row per wave
    const float scale = __expf(scale_param[(gid >> 11) & 7]);

    // q load (independent) + mask ballot
    float qv = q[(size_t)gid * DIM + lane];
    size_t mmrow = (size_t)gid * KNN;
    bool mybit = mask_is_int ? (((const int*)mem_mask)[mmrow + (lane & 31)] != 0)
                             : (((const unsigned char*)mem_mask)[mmrow + (lane & 31)] != 0);
    const unsigned int mb = (unsigned int)__ballot(mybit);

    const float* rowp = mem_kv + (size_t)gid * (KNN * 2 * DIM);
    const float* lanep = rowp + lane * 4;

    F4 dat[2][4];
    LOADG(0, 0)
    LOADG(1, 1)

    // q l2-norm while first groups are in flight
    float ssq = qv * qv;
    #pragma unroll
    for (int m2 = 1; m2 < 64; m2 <<= 1) ssq += __shfl_xor(ssq, m2);
    float qn = qv / fmaxf(sqrtf(ssq), 1e-12f);
    qnB[(size_t)gid * DIM + lane] = f2bf(qn);
    F4 qd;
    #pragma unroll
    for (int e = 0; e < 4; e++) qd.f[e] = __shfl(qn, i16 * 4 + e);

    float mrun = NEGF, lrun = 0.f;
    float a0 = 0.f, a1 = 0.f, a2 = 0.f, a3 = 0.f;

    COMPUTE(0, 0)
    LOADG(0, 2)
    COMPUTE(1, 1)
    LOADG(1, 3)
    COMPUTE(0, 2)
    COMPUTE(1, 3)

    // combine j-parities
    float ls = lrun + __shfl_xor(lrun, 32);
    a0 += __shfl_xor(a0, 32);
    a1 += __shfl_xor(a1, 32);
    a2 += __shfl_xor(a2, 32);
    a3 += __shfl_xor(a3, 32);
    if (kv == 1 && h2 == 0) {
        F4 o; o.f[0] = a0; o.f[1] = a1; o.f[2] = a2; o.f[3] = a3;
        *(float4*)(maccG + (size_t)gid * DIM + i16 * 4) = o.v;
    }
    if (lane == 0) { mG[gid] = mrun; lG[gid] = ls; }
}

__global__ __launch_bounds__(256) void flash_kernel(
    const float* __restrict__ scale_param,  // H
    const float* __restrict__ mask,         // B,S float
    const unsigned short* __restrict__ knB, // B,S,D bf16 (l2-normed k)
    const unsigned short* __restrict__ vT,  // B,D,S bf16
    const unsigned short* __restrict__ qnB, // B,H,S,D bf16 (l2-normed q)
    const float* __restrict__ maccG,        // B,H,S,D mem-branch acc
    const float* __restrict__ mG,           // B,H,S
    const float* __restrict__ lG,           // B,H,S
    float* __restrict__ out)                // B,H,S,D
{
    __shared__ float maccs[QT][DIM + 4];
    __shared__ float mmem_s[QT], lmem_s[QT];
    __shared__ unsigned short fragbuf[4][2][2][4][16][8]; // per-wave P in B-frag layout
    __shared__ float corr_s[4][QT];
    __shared__ float mlw[4][2][QT];
    __shared__ float linv_s[QT];

    const int tid = threadIdx.x;
    const int w = tid >> 6;
    const int lane = tid & 63;
    const int g = lane >> 4;
    const int c = lane & 15;
    const int bid = blockIdx.x;
    const int qt = 63 - (bid & 63);       // heavy tiles first
    const int bh = bid >> 6;
    const int b = bh >> 3;
    const int h = bh & 7;
    const int i0 = qt * QT;

    const float scale = __expf(scale_param[h]);

    // ---- load mem-branch partials into LDS; q A-frags from qnB ----
    {
        int i = tid >> 3, d0 = (tid & 7) * 8;
        const float* src = maccG + ((size_t)bh * SEQ + i0 + i) * DIM + d0;
        *(float4*)&maccs[i][d0]     = *(const float4*)src;
        *(float4*)&maccs[i][d0 + 4] = *(const float4*)(src + 4);
        if (tid < QT) {
            mmem_s[tid] = mG[(size_t)bh * SEQ + i0 + tid];
            lmem_s[tid] = lG[(size_t)bh * SEQ + i0 + tid];
        }
    }
    bf16x8 qa[2][2];
    #pragma unroll
    for (int mt = 0; mt < 2; mt++)
        #pragma unroll
        for (int kc = 0; kc < 2; kc++) {
            S8 t;
            t.u4 = *(const uint4*)(qnB + ((size_t)bh * SEQ + i0 + mt * 16 + c) * DIM + kc * 32 + g * 8);
            qa[mt][kc] = t.b;
        }

    // ---------------- Flash over key tiles (waves split jt) ----------------
    f32x4 oacc[4][2];
    #pragma unroll
    for (int mtd = 0; mtd < 4; mtd++)
        #pragma unroll
        for (int ni = 0; ni < 2; ni++)
            #pragma unroll
            for (int r = 0; r < 4; r++) oacc[mtd][ni][r] = 0.f;
    float mrow[2][4], lrow[2][4];
    #pragma unroll
    for (int mt = 0; mt < 2; mt++)
        #pragma unroll
        for (int r = 0; r < 4; r++) { mrow[mt][r] = NEGF; lrow[mt][r] = 0.f; }

    const int nkt = ((i0 + QT - 1) >> 6) + 1;
    const unsigned short* knBb = knB + (size_t)b * SEQ * DIM;
    const unsigned short* vTb  = vT  + (size_t)b * DIM * SEQ;

    for (int jt = w; jt < nkt; jt += 4) {
        const int jb = jt * KT;

        bf16x8 va[4][2];
        #pragma unroll
        for (int mtd = 0; mtd < 4; mtd++)
            #pragma unroll
            for (int kk2 = 0; kk2 < 2; kk2++) {
                const unsigned short* vp = vTb + (size_t)(mtd * 16 + c) * SEQ + jb + kk2 * 32 + 4 * g;
                S8 t; t.u2[0] = *(const uint2*)vp; t.u2[1] = *(const uint2*)(vp + 16);
                va[mtd][kk2] = t.b;
            }

        f32x4 sacc[2][4];
        #pragma unroll
        for (int mt = 0; mt < 2; mt++)
            #pragma unroll
            for (int nt = 0; nt < 4; nt++)
                #pragma unroll
                for (int r = 0; r < 4; r++) sacc[mt][nt][r] = 0.f;
        #pragma unroll
        for (int kc = 0; kc < 2; kc++) {
            #pragma unroll
            for (int nt = 0; nt < 4; nt++) {
                S8 kb; kb.u4 = *(const uint4*)(knBb + (size_t)(jb + nt * 16 + c) * DIM + kc * 32 + g * 8);
                #pragma unroll
                for (int mt = 0; mt < 2; mt++)
                    sacc[mt][nt] = __builtin_amdgcn_mfma_f32_16x16x32_bf16(qa[mt][kc], kb.b, sacc[mt][nt], 0, 0, 0);
            }
        }

        float mv4[4];
        #pragma unroll
        for (int nt = 0; nt < 4; nt++) mv4[nt] = mask[b * SEQ + jb + nt * 16 + c];
        const bool docausal = (jb + 63 > i0);
        float corr[2][4];
        #pragma unroll
        for (int mt = 0; mt < 2; mt++) {
            #pragma unroll
            for (int nt = 0; nt < 4; nt++)
                #pragma unroll
                for (int r = 0; r < 4; r++) {
                    float s = sacc[mt][nt][r] * scale + NEGF * (1.f - mv4[nt]);
                    if (docausal) {
                        int j = jb + nt * 16 + c;
                        int i = i0 + mt * 16 + 4 * g + r;
                        if (j > i) s = NEGF;
                    }
                    sacc[mt][nt][r] = s;
                }
            #pragma unroll
            for (int r = 0; r < 4; r++) {
                float rmax = fmaxf(fmaxf(sacc[mt][0][r], sacc[mt][1][r]),
                                   fmaxf(sacc[mt][2][r], sacc[mt][3][r]));
                #pragma unroll
                for (int m2 = 1; m2 < 16; m2 <<= 1) rmax = fmaxf(rmax, __shfl_xor(rmax, m2));
                float mnew = fmaxf(mrow[mt][r], rmax);
                corr[mt][r] = __expf(mrow[mt][r] - mnew);
                mrow[mt][r] = mnew;
            }
        }

        #pragma unroll
        for (int mt = 0; mt < 2; mt++) {
            float psum[4] = {0.f, 0.f, 0.f, 0.f};
            #pragma unroll
            for (int nt = 0; nt < 4; nt++)
                #pragma unroll
                for (int r = 0; r < 4; r++) {
                    float p = __expf(sacc[mt][nt][r] - mrow[mt][r]);
                    psum[r] += p;
                    fragbuf[w][mt][nt >> 1][c >> 2][4 * g + r][(c & 3) + 4 * (nt & 1)] = f2bf(p);
                }
            #pragma unroll
            for (int r = 0; r < 4; r++) {
                float ps = psum[r];
                #pragma unroll
                for (int m2 = 1; m2 < 16; m2 <<= 1) ps += __shfl_xor(ps, m2);
                lrow[mt][r] = lrow[mt][r] * corr[mt][r] + ps;
            }
        }

        if (c == 0) {
            #pragma unroll
            for (int mt = 0; mt < 2; mt++)
                #pragma unroll
                for (int r = 0; r < 4; r++)
                    corr_s[w][mt * 16 + 4 * g + r] = corr[mt][r];
        }
        float cf0 = corr_s[w][c];
        float cf1 = corr_s[w][16 + c];
        #pragma unroll
        for (int mtd = 0; mtd < 4; mtd++)
            #pragma unroll
            for (int r = 0; r < 4; r++) { oacc[mtd][0][r] *= cf0; oacc[mtd][1][r] *= cf1; }

        #pragma unroll
        for (int kk2 = 0; kk2 < 2; kk2++)
            #pragma unroll
            for (int ni = 0; ni < 2; ni++) {
                S8 pb; pb.u4 = *(const uint4*)&fragbuf[w][ni][kk2][g][c][0];
                #pragma unroll
                for (int mtd = 0; mtd < 4; mtd++)
                    oacc[mtd][ni] = __builtin_amdgcn_mfma_f32_16x16x32_bf16(va[mtd][kk2], pb.b, oacc[mtd][ni], 0, 0, 0);
            }
    }

    // ---------------- merge: 4 wave-partials + mem branch ----------------
    if (c == 0) {
        #pragma unroll
        for (int mt = 0; mt < 2; mt++)
            #pragma unroll
            for (int r = 0; r < 4; r++) {
                mlw[w][0][mt * 16 + 4 * g + r] = mrow[mt][r];
                mlw[w][1][mt * 16 + 4 * g + r] = lrow[mt][r];
            }
    }
    __syncthreads();
    {
        int i = tid >> 3;
        int d0 = (tid & 7) * 8;
        float mM = mmem_s[i];
        #pragma unroll
        for (int w2 = 0; w2 < 4; w2++) mM = fmaxf(mM, mlw[w2][0][i]);
        float em = __expf(mmem_s[i] - mM);
        float L = lmem_s[i] * em;
        #pragma unroll
        for (int w2 = 0; w2 < 4; w2++) L += mlw[w2][1][i] * __expf(mlw[w2][0][i] - mM);
        #pragma unroll
        for (int e = 0; e < 8; e++) maccs[i][d0 + e] *= em;
        if ((tid & 7) == 0) linv_s[i] = 1.f / L;
        if ((tid & 7) == 1) corr_s[0][i] = mM;   // stash global max
    }
    __syncthreads();
    float ew0 = __expf(mlw[w][0][c]      - corr_s[0][c]);
    float ew1 = __expf(mlw[w][0][16 + c] - corr_s[0][16 + c]);
    for (int w2 = 0; w2 < 4; w2++) {
        if (w == w2) {
            #pragma unroll
            for (int mtd = 0; mtd < 4; mtd++)
                #pragma unroll
                for (int r = 0; r < 4; r++) {
                    maccs[c][mtd * 16 + 4 * g + r]      += oacc[mtd][0][r] * ew0;
                    maccs[16 + c][mtd * 16 + 4 * g + r] += oacc[mtd][1][r] * ew1;
                }
        }
        __syncthreads();
    }
    {
        int i = tid >> 3;
        int d0 = (tid & 7) * 8;
        float inv = linv_s[i];
        F4 o0, o1;
        o0.v = *(const float4*)&maccs[i][d0];
        o1.v = *(const float4*)&maccs[i][d0 + 4];
        #pragma unroll
        for (int e = 0; e < 4; e++) { o0.f[e] *= inv; o1.f[e] *= inv; }
        float* op = out + ((size_t)bh * SEQ + i0 + i) * DIM + d0;
        *(float4*)op = o0.v;
        *(float4*)(op + 4) = o1.v;
    }
}

extern "C" void kernel_launch(void* const* d_in, const int* in_sizes, int n_in,
                              void* d_out, int out_size, void* d_ws, size_t ws_size,
                              hipStream_t stream) {
    const float* q           = (const float*)d_in[0];
    const float* k           = (const float*)d_in[1];
    const float* v           = (const float*)d_in[2];
    const float* scale_param = (const float*)d_in[3];
    const float* mem_kv      = (const float*)d_in[4];
    const float* mask        = (const float*)d_in[5];
    const void*  mem_mask    = d_in[6];
    float* out = (float*)d_out;

    char* base = (char*)d_ws;
    int* flag           = (int*)base;
    unsigned short* knB = (unsigned short*)(base + 1024);
    unsigned short* vT  = (unsigned short*)(base + 1024 + (512ull << 10));
    unsigned short* qnB = (unsigned short*)(base + 1024 + (1ull << 20));
    float* maccG        = (float*)(base + 1024 + (5ull << 20));
    float* mG           = (float*)(base + 1024 + (13ull << 20));
    float* lG           = (float*)(base + 1024 + (13ull << 20) + (256ull << 10));

    prep_kernel<<<dim3(BATCH * SEQ / 64), dim3(256), 0, stream>>>(
        k, v, (const unsigned char*)mem_mask, knB, vT, flag);
    mem_kernel<<<dim3(BATCH * HEADS * SEQ / 4), dim3(256), 0, stream>>>(
        q, scale_param, mem_kv, mem_mask, flag, qnB, maccG, mG, lG);
    flash_kernel<<<dim3(BATCH * HEADS * (SEQ / QT)), dim3(256), 0, stream>>>(
        scale_param, mask, knB, vT, qnB, maccG, mG, lG, out);
}

// Round 10
// 158.353 us; speedup vs baseline: 1.4446x; 1.0122x over previous
//
#include <hip/hip_runtime.h>
#include <float.h>

#define HEADS 8
#define DIM 64
#define BATCH 2
#define SEQ 2048
#define KNN 32
#define QT 32
#define KT 64
#define NEGF (-3.402823466e38f)

typedef float f32x4 __attribute__((ext_vector_type(4)));
typedef __bf16 bf16x8 __attribute__((ext_vector_type(8)));

union F4 { float4 v; f32x4 e; float f[4]; };
union S8 { bf16x8 b; unsigned int u[4]; unsigned short us[8]; uint4 u4; uint2 u2[2]; };

__device__ __forceinline__ unsigned short f2bf(float x) {
    unsigned int u = __float_as_uint(x);
    u = (u + 0x7fffu + ((u >> 16) & 1u)) >> 16;
    return (unsigned short)u;
}

// ws layout (bytes):
//   flag  @ 0
//   knB   @ 1024            bf16 (B,S,D)        512 KB
//   vT    @ 1024 + 512K     bf16 (B,D,S)        512 KB
//   qnB   @ 1024 + 1M       bf16 (B,H,S,D)      4 MB
//   maccG @ 1024 + 5M       f32  (B,H,S,D)      8 MB
//   mG    @ 1024 + 13M      f32  (B,H,S)        128 KB
//   lG    @ 1024 + 13M+256K f32  (B,H,S)        128 KB

__global__ __launch_bounds__(256) void prep_kernel(const float* __restrict__ k,
                                                   const float* __restrict__ v,
                                                   const unsigned char* __restrict__ mmraw,
                                                   unsigned short* __restrict__ knB,
                                                   unsigned short* __restrict__ vT,
                                                   int* __restrict__ flag) {
    __shared__ float vt_s[64][65];
    const int w = threadIdx.x >> 6, lane = threadIdx.x & 63;
    const int s0 = blockIdx.x * 64;       // global row index b*SEQ+s
    const int b = s0 >> 11;
    for (int rr = 0; rr < 16; rr++) {
        const int sl = w * 16 + rr;
        const int row = s0 + sl;
        float kv = k[(size_t)row * DIM + lane];
        float ssq = kv * kv;
        #pragma unroll
        for (int m = 1; m < 64; m <<= 1) ssq += __shfl_xor(ssq, m);
        float kn = kv / fmaxf(sqrtf(ssq), 1e-12f);
        knB[(size_t)row * DIM + lane] = f2bf(kn);
        vt_s[sl][lane] = v[(size_t)row * DIM + lane];
    }
    __syncthreads();
    {   // transposed V write: thread -> (d, 16-s chunk), 32B contiguous stores
        const int d = threadIdx.x >> 2;
        const int sc = (threadIdx.x & 3) * 16;
        const int s_base = s0 & 2047;
        unsigned short tmp[16];
        #pragma unroll
        for (int e = 0; e < 16; e++) tmp[e] = f2bf(vt_s[sc + e][d]);
        unsigned short* dst = vT + ((size_t)b * DIM + d) * SEQ + s_base + sc;
        *(uint4*)dst = *(uint4*)&tmp[0];
        *(uint4*)(dst + 8) = *(uint4*)&tmp[8];
    }
    if (blockIdx.x == 0 && w == 0) {
        int bad = 0;
        #pragma unroll
        for (int t = 0; t < 8; t++) {
            int idx = t * 64 + lane;
            if ((idx & 3) != 0 && mmraw[idx] != 0) bad = 1;
        }
        unsigned long long anybad = __ballot(bad);
        if (lane == 0) flag[0] = (anybad == 0ULL) ? 1 : 0;
    }
}

// Mem-branch streamer v4: lane-owns-j layout, minimal cross-lane traffic.
// Per row: 1 mask load + 1 q load + 8 k-loads (in-lane dot) + 8 v-loads,
// all issued in one window; ~43 DS ops/row (was ~105), 2 exp/row (was ~40).
__global__ __launch_bounds__(256, 4) void mem_kernel(
    const float* __restrict__ q,           // B,H,S,D
    const float* __restrict__ scale_param, // H
    const float* __restrict__ mem_kv,      // B,H,S,KNN,2,D
    const void*  __restrict__ mem_mask,    // B,H,S,KNN
    const int*   __restrict__ flagp,
    unsigned short* __restrict__ qnB,      // out: bf16 normalized q
    float* __restrict__ maccG,             // out: (B,H,S,D) weighted mem_v (unnormalized)
    float* __restrict__ mG,                // out: (B,H,S) row max
    float* __restrict__ lG)                // out: (B,H,S) row sum
{
    __shared__ float qn_s[4][64];
    __shared__ float p_s[4][32];
    const int w = threadIdx.x >> 6, lane = threadIdx.x & 63;
    const int mask_is_int = flagp[0];
    const int gid = blockIdx.x * 4 + w;    // one row per wave
    const float scale = __expf(scale_param[(gid >> 11) & 7]);
    const float* rowp = mem_kv + (size_t)gid * (KNN * 2 * DIM);

    // own mask bit (j = lane&31, duplicated across halves)
    const int j1 = lane & 31, dh = lane >> 5;
    bool mybit;
    {
        size_t mmrow = (size_t)gid * KNN;
        mybit = mask_is_int ? (((const int*)mem_mask)[mmrow + j1] != 0)
                            : (((const unsigned char*)mem_mask)[mmrow + j1] != 0);
    }
    const unsigned int mb = (unsigned int)__ballot(mybit);  // low 32 bits = j bits

    // q load (independent)
    float qv = q[(size_t)gid * DIM + lane];

    // phase-1 k loads: lane covers mem_k[j1][dh*32 .. dh*32+31], predicated on own bit
    F4 dk[8];
    #pragma unroll
    for (int i = 0; i < 8; i++) dk[i].e = 0.f;
    {
        const float* kbase = rowp + j1 * (2 * DIM) + dh * 32;
        if (mybit) {
            #pragma unroll
            for (int i = 0; i < 8; i++) dk[i].e = *(const f32x4*)(kbase + 4 * i);
        }
    }
    // phase-2 v loads: lane group g covers mem_v[4t+g][c16*4 .. +3]
    const int g = lane >> 4, c16 = lane & 15;
    F4 dv[8];
    #pragma unroll
    for (int t = 0; t < 8; t++) {
        dv[t].e = 0.f;
        const int j2 = 4 * t + g;
        if ((mb >> j2) & 1u)
            dv[t].e = *(const f32x4*)(rowp + j2 * (2 * DIM) + DIM + c16 * 4);
    }

    // q l2-norm while loads are in flight
    float ssq = qv * qv;
    #pragma unroll
    for (int m2 = 1; m2 < 64; m2 <<= 1) ssq += __shfl_xor(ssq, m2);
    float qn = qv / fmaxf(sqrtf(ssq), 1e-12f);
    qnB[(size_t)gid * DIM + lane] = f2bf(qn);
    qn_s[w][lane] = qn;

    // in-lane dot over own d-half (qn via LDS broadcast reads)
    float s = 0.f;
    #pragma unroll
    for (int i = 0; i < 8; i++) {
        F4 qq; qq.v = *(const float4*)&qn_s[w][dh * 32 + 4 * i];
        s += dk[i].f[0] * qq.f[0] + dk[i].f[1] * qq.f[1]
           + dk[i].f[2] * qq.f[2] + dk[i].f[3] * qq.f[3];
    }
    s += __shfl_xor(s, 32);                 // combine d-halves; lane now has full s_j
    s = mybit ? s * scale : NEGF;

    // softmax over 32 j (within-half reduce; halves hold identical j sets)
    float mx = s;
    #pragma unroll
    for (int m2 = 1; m2 < 32; m2 <<= 1) mx = fmaxf(mx, __shfl_xor(mx, m2));
    float p = __expf(s - mx);               // masked -> underflow 0 (or garbage-1 if all masked, zeroed at merge)
    float ls = p;
    #pragma unroll
    for (int m2 = 1; m2 < 32; m2 <<= 1) ls += __shfl_xor(ls, m2);
    if (lane < 32) p_s[w][lane] = p;

    // weighted V, in-lane per d-quarter; j split across 4 lane-groups
    f32x4 acc = 0.f;
    #pragma unroll
    for (int t = 0; t < 8; t++) {
        float pv = p_s[w][4 * t + g];
        #pragma unroll
        for (int e = 0; e < 4; e++) acc[e] += pv * dv[t].f[e];
    }
    #pragma unroll
    for (int e = 0; e < 4; e++) {
        acc[e] += __shfl_xor(acc[e], 16);
        acc[e] += __shfl_xor(acc[e], 32);
    }
    if (g == 0) {
        F4 o; o.e = acc;
        *(float4*)(maccG + (size_t)gid * DIM + c16 * 4) = o.v;
    }
    if (lane == 0) { mG[gid] = mx; lG[gid] = ls; }
}

__global__ __launch_bounds__(256) void flash_kernel(
    const float* __restrict__ scale_param,  // H
    const float* __restrict__ mask,         // B,S float
    const unsigned short* __restrict__ knB, // B,S,D bf16 (l2-normed k)
    const unsigned short* __restrict__ vT,  // B,D,S bf16
    const unsigned short* __restrict__ qnB, // B,H,S,D bf16 (l2-normed q)
    const float* __restrict__ maccG,        // B,H,S,D mem-branch acc
    const float* __restrict__ mG,           // B,H,S
    const float* __restrict__ lG,           // B,H,S
    float* __restrict__ out)                // B,H,S,D
{
    __shared__ float maccs[QT][DIM + 4];
    __shared__ float mmem_s[QT], lmem_s[QT];
    __shared__ unsigned short fragbuf[4][2][2][4][16][8]; // per-wave P in B-frag layout
    __shared__ float corr_s[4][QT];
    __shared__ float mlw[4][2][QT];
    __shared__ float linv_s[QT];

    const int tid = threadIdx.x;
    const int w = tid >> 6;
    const int lane = tid & 63;
    const int g = lane >> 4;
    const int c = lane & 15;
    const int bid = blockIdx.x;
    const int qt = 63 - (bid & 63);       // heavy tiles first
    const int bh = bid >> 6;
    const int b = bh >> 3;
    const int h = bh & 7;
    const int i0 = qt * QT;

    const float scale = __expf(scale_param[h]);

    // ---- load mem-branch partials into LDS; q A-frags from qnB ----
    {
        int i = tid >> 3, d0 = (tid & 7) * 8;
        const float* src = maccG + ((size_t)bh * SEQ + i0 + i) * DIM + d0;
        *(float4*)&maccs[i][d0]     = *(const float4*)src;
        *(float4*)&maccs[i][d0 + 4] = *(const float4*)(src + 4);
        if (tid < QT) {
            mmem_s[tid] = mG[(size_t)bh * SEQ + i0 + tid];
            lmem_s[tid] = lG[(size_t)bh * SEQ + i0 + tid];
        }
    }
    bf16x8 qa[2][2];
    #pragma unroll
    for (int mt = 0; mt < 2; mt++)
        #pragma unroll
        for (int kc = 0; kc < 2; kc++) {
            S8 t;
            t.u4 = *(const uint4*)(qnB + ((size_t)bh * SEQ + i0 + mt * 16 + c) * DIM + kc * 32 + g * 8);
            qa[mt][kc] = t.b;
        }

    // ---------------- Flash over key tiles (waves split jt) ----------------
    f32x4 oacc[4][2];
    #pragma unroll
    for (int mtd = 0; mtd < 4; mtd++)
        #pragma unroll
        for (int ni = 0; ni < 2; ni++)
            #pragma unroll
            for (int r = 0; r < 4; r++) oacc[mtd][ni][r] = 0.f;
    float mrow[2][4], lrow[2][4];
    #pragma unroll
    for (int mt = 0; mt < 2; mt++)
        #pragma unroll
        for (int r = 0; r < 4; r++) { mrow[mt][r] = NEGF; lrow[mt][r] = 0.f; }

    const int nkt = ((i0 + QT - 1) >> 6) + 1;
    const unsigned short* knBb = knB + (size_t)b * SEQ * DIM;
    const unsigned short* vTb  = vT  + (size_t)b * DIM * SEQ;

    for (int jt = w; jt < nkt; jt += 4) {
        const int jb = jt * KT;

        bf16x8 va[4][2];
        #pragma unroll
        for (int mtd = 0; mtd < 4; mtd++)
            #pragma unroll
            for (int kk2 = 0; kk2 < 2; kk2++) {
                const unsigned short* vp = vTb + (size_t)(mtd * 16 + c) * SEQ + jb + kk2 * 32 + 4 * g;
                S8 t; t.u2[0] = *(const uint2*)vp; t.u2[1] = *(const uint2*)(vp + 16);
                va[mtd][kk2] = t.b;
            }

        f32x4 sacc[2][4];
        #pragma unroll
        for (int mt = 0; mt < 2; mt++)
            #pragma unroll
            for (int nt = 0; nt < 4; nt++)
                #pragma unroll
                for (int r = 0; r < 4; r++) sacc[mt][nt][r] = 0.f;
        #pragma unroll
        for (int kc = 0; kc < 2; kc++) {
            #pragma unroll
            for (int nt = 0; nt < 4; nt++) {
                S8 kb; kb.u4 = *(const uint4*)(knBb + (size_t)(jb + nt * 16 + c) * DIM + kc * 32 + g * 8);
                #pragma unroll
                for (int mt = 0; mt < 2; mt++)
                    sacc[mt][nt] = __builtin_amdgcn_mfma_f32_16x16x32_bf16(qa[mt][kc], kb.b, sacc[mt][nt], 0, 0, 0);
            }
        }

        float mv4[4];
        #pragma unroll
        for (int nt = 0; nt < 4; nt++) mv4[nt] = mask[b * SEQ + jb + nt * 16 + c];
        const bool docausal = (jb + 63 > i0);
        float corr[2][4];
        #pragma unroll
        for (int mt = 0; mt < 2; mt++) {
            #pragma unroll
            for (int nt = 0; nt < 4; nt++)
                #pragma unroll
                for (int r = 0; r < 4; r++) {
                    float s = sacc[mt][nt][r] * scale + NEGF * (1.f - mv4[nt]);
                    if (docausal) {
                        int j = jb + nt * 16 + c;
                        int i = i0 + mt * 16 + 4 * g + r;
                        if (j > i) s = NEGF;
                    }
                    sacc[mt][nt][r] = s;
                }
            #pragma unroll
            for (int r = 0; r < 4; r++) {
                float rmax = fmaxf(fmaxf(sacc[mt][0][r], sacc[mt][1][r]),
                                   fmaxf(sacc[mt][2][r], sacc[mt][3][r]));
                #pragma unroll
                for (int m2 = 1; m2 < 16; m2 <<= 1) rmax = fmaxf(rmax, __shfl_xor(rmax, m2));
                float mnew = fmaxf(mrow[mt][r], rmax);
                corr[mt][r] = __expf(mrow[mt][r] - mnew);
                mrow[mt][r] = mnew;
            }
        }

        #pragma unroll
        for (int mt = 0; mt < 2; mt++) {
            float psum[4] = {0.f, 0.f, 0.f, 0.f};
            #pragma unroll
            for (int nt = 0; nt < 4; nt++)
                #pragma unroll
                for (int r = 0; r < 4; r++) {
                    float p = __expf(sacc[mt][nt][r] - mrow[mt][r]);
                    psum[r] += p;
                    fragbuf[w][mt][nt >> 1][c >> 2][4 * g + r][(c & 3) + 4 * (nt & 1)] = f2bf(p);
                }
            #pragma unroll
            for (int r = 0; r < 4; r++) {
                float ps = psum[r];
                #pragma unroll
                for (int m2 = 1; m2 < 16; m2 <<= 1) ps += __shfl_xor(ps, m2);
                lrow[mt][r] = lrow[mt][r] * corr[mt][r] + ps;
            }
        }

        if (c == 0) {
            #pragma unroll
            for (int mt = 0; mt < 2; mt++)
                #pragma unroll
                for (int r = 0; r < 4; r++)
                    corr_s[w][mt * 16 + 4 * g + r] = corr[mt][r];
        }
        float cf0 = corr_s[w][c];
        float cf1 = corr_s[w][16 + c];
        #pragma unroll
        for (int mtd = 0; mtd < 4; mtd++)
            #pragma unroll
            for (int r = 0; r < 4; r++) { oacc[mtd][0][r] *= cf0; oacc[mtd][1][r] *= cf1; }

        #pragma unroll
        for (int kk2 = 0; kk2 < 2; kk2++)
            #pragma unroll
            for (int ni = 0; ni < 2; ni++) {
                S8 pb; pb.u4 = *(const uint4*)&fragbuf[w][ni][kk2][g][c][0];
                #pragma unroll
                for (int mtd = 0; mtd < 4; mtd++)
                    oacc[mtd][ni] = __builtin_amdgcn_mfma_f32_16x16x32_bf16(va[mtd][kk2], pb.b, oacc[mtd][ni], 0, 0, 0);
            }
    }

    // ---------------- merge: 4 wave-partials + mem branch ----------------
    if (c == 0) {
        #pragma unroll
        for (int mt = 0; mt < 2; mt++)
            #pragma unroll
            for (int r = 0; r < 4; r++) {
                mlw[w][0][mt * 16 + 4 * g + r] = mrow[mt][r];
                mlw[w][1][mt * 16 + 4 * g + r] = lrow[mt][r];
            }
    }
    __syncthreads();
    {
        int i = tid >> 3;
        int d0 = (tid & 7) * 8;
        float mM = mmem_s[i];
        #pragma unroll
        for (int w2 = 0; w2 < 4; w2++) mM = fmaxf(mM, mlw[w2][0][i]);
        float em = __expf(mmem_s[i] - mM);
        float L = lmem_s[i] * em;
        #pragma unroll
        for (int w2 = 0; w2 < 4; w2++) L += mlw[w2][1][i] * __expf(mlw[w2][0][i] - mM);
        #pragma unroll
        for (int e = 0; e < 8; e++) maccs[i][d0 + e] *= em;
        if ((tid & 7) == 0) linv_s[i] = 1.f / L;
        if ((tid & 7) == 1) corr_s[0][i] = mM;   // stash global max
    }
    __syncthreads();
    float ew0 = __expf(mlw[w][0][c]      - corr_s[0][c]);
    float ew1 = __expf(mlw[w][0][16 + c] - corr_s[0][16 + c]);
    for (int w2 = 0; w2 < 4; w2++) {
        if (w == w2) {
            #pragma unroll
            for (int mtd = 0; mtd < 4; mtd++)
                #pragma unroll
                for (int r = 0; r < 4; r++) {
                    maccs[c][mtd * 16 + 4 * g + r]      += oacc[mtd][0][r] * ew0;
                    maccs[16 + c][mtd * 16 + 4 * g + r] += oacc[mtd][1][r] * ew1;
                }
        }
        __syncthreads();
    }
    {
        int i = tid >> 3;
        int d0 = (tid & 7) * 8;
        float inv = linv_s[i];
        F4 o0, o1;
        o0.v = *(const float4*)&maccs[i][d0];
        o1.v = *(const float4*)&maccs[i][d0 + 4];
        #pragma unroll
        for (int e = 0; e < 4; e++) { o0.f[e] *= inv; o1.f[e] *= inv; }
        float* op = out + ((size_t)bh * SEQ + i0 + i) * DIM + d0;
        *(float4*)op = o0.v;
        *(float4*)(op + 4) = o1.v;
    }
}

extern "C" void kernel_launch(void* const* d_in, const int* in_sizes, int n_in,
                              void* d_out, int out_size, void* d_ws, size_t ws_size,
                              hipStream_t stream) {
    const float* q           = (const float*)d_in[0];
    const float* k           = (const float*)d_in[1];
    const float* v           = (const float*)d_in[2];
    const float* scale_param = (const float*)d_in[3];
    const float* mem_kv      = (const float*)d_in[4];
    const float* mask        = (const float*)d_in[5];
    const void*  mem_mask    = d_in[6];
    float* out = (float*)d_out;

    char* base = (char*)d_ws;
    int* flag           = (int*)base;
    unsigned short* knB = (unsigned short*)(base + 1024);
    unsigned short* vT  = (unsigned short*)(base + 1024 + (512ull << 10));
    unsigned short* qnB = (unsigned short*)(base + 1024 + (1ull << 20));
    float* maccG        = (float*)(base + 1024 + (5ull << 20));
    float* mG           = (float*)(base + 1024 + (13ull << 20));
    float* lG           = (float*)(base + 1024 + (13ull << 20) + (256ull << 10));

    prep_kernel<<<dim3(BATCH * SEQ / 64), dim3(256), 0, stream>>>(
        k, v, (const unsigned char*)mem_mask, knB, vT, flag);
    mem_kernel<<<dim3(BATCH * HEADS * SEQ / 4), dim3(256), 0, stream>>>(
        q, scale_param, mem_kv, mem_mask, flag, qnB, maccG, mG, lG);
    flash_kernel<<<dim3(BATCH * HEADS * (SEQ / QT)), dim3(256), 0, stream>>>(
        scale_param, mask, knB, vT, qnB, maccG, mG, lG, out);
}